// Round 18
// baseline (213.160 us; speedup 1.0000x reference)
//
#include <hip/hip_runtime.h>
#include <hip/hip_bf16.h>

// MPNN: B=8, N=36, H=64, STEPS=5
// messages[b,j,k] = (1/N^2) * sum_{i,l} edge[b,i,j,k,l] * nodes[b,i,l]
// nodes = GRUCell(messages, nodes) * mask, repeated STEPS times.
//
// PIPELINED structure: 13 launches of one heterogeneous "mega" kernel.
// Launch t runs (as disjoint block ranges, deps all cross-launch):
//   cvt(batch t)            [t<8]  : f32 einsum partial + bf16 edge copy
//   gru1(batch t-1)                : partial -> nodes1
//   step_s(batch t-s), s=2..5      : fused bf16 einsum + GRU
// The ~91 us conversion wall absorbs the step/GRU time that previously ran
// serially after it.

#define BB 8
#define NN 36
#define HH 64
#define NBJ (BB * NN)
#define INVN2 (1.0f / (float)(NN * NN))

typedef unsigned u32x4 __attribute__((ext_vector_type(4)));

__device__ __forceinline__ unsigned pack_bf16_2(float lo, float hi) {
    __hip_bfloat16 a = __float2bfloat16(lo);
    __hip_bfloat16 b = __float2bfloat16(hi);
    unsigned ua = *reinterpret_cast<unsigned short*>(&a);
    unsigned ub = *reinterpret_cast<unsigned short*>(&b);
    return ua | (ub << 16);
}

// GRU cell: lane t computes output dim t from LDS-staged ms/hs vectors.
__device__ __forceinline__ float gru_lane(
    const float* __restrict__ ms, const float* __restrict__ hs, int t,
    const float* __restrict__ w_ih, const float* __restrict__ w_hh,
    const float* __restrict__ b_ih, const float* __restrict__ b_hh)
{
    float gi0 = b_ih[t], gi1 = b_ih[HH + t], gi2 = b_ih[2 * HH + t];
    float gh0 = b_hh[t], gh1 = b_hh[HH + t], gh2 = b_hh[2 * HH + t];

    const float4* __restrict__ wi0 = (const float4*)(w_ih + (0 * HH + t) * HH);
    const float4* __restrict__ wi1 = (const float4*)(w_ih + (1 * HH + t) * HH);
    const float4* __restrict__ wi2 = (const float4*)(w_ih + (2 * HH + t) * HH);
    const float4* __restrict__ wh0 = (const float4*)(w_hh + (0 * HH + t) * HH);
    const float4* __restrict__ wh1 = (const float4*)(w_hh + (1 * HH + t) * HH);
    const float4* __restrict__ wh2 = (const float4*)(w_hh + (2 * HH + t) * HH);

    #pragma unroll
    for (int k4 = 0; k4 < HH / 4; ++k4) {
        const float4 mv = *(const float4*)&ms[k4 * 4];
        const float4 hv = *(const float4*)&hs[k4 * 4];
        float4 a;
        a = wi0[k4]; gi0 += a.x * mv.x + a.y * mv.y + a.z * mv.z + a.w * mv.w;
        a = wi1[k4]; gi1 += a.x * mv.x + a.y * mv.y + a.z * mv.z + a.w * mv.w;
        a = wi2[k4]; gi2 += a.x * mv.x + a.y * mv.y + a.z * mv.z + a.w * mv.w;
        a = wh0[k4]; gh0 += a.x * hv.x + a.y * hv.y + a.z * hv.z + a.w * hv.w;
        a = wh1[k4]; gh1 += a.x * hv.x + a.y * hv.y + a.z * hv.z + a.w * hv.w;
        a = wh2[k4]; gh2 += a.x * hv.x + a.y * hv.y + a.z * hv.z + a.w * hv.w;
    }
    const float r = 1.f / (1.f + expf(-(gi0 + gh0)));
    const float z = 1.f / (1.f + expf(-(gi1 + gh1)));
    const float n = tanhf(gi2 + r * gh2);
    return (1.f - z) * n + z * hs[t];
}

// ---------------------------------------------------------------------------
// Mega kernel: block ranges = [cvt 324][gru 9][slot0 36][slot1 36][slot2 36][slot3 36]
// ---------------------------------------------------------------------------
__global__ __launch_bounds__(256, 2) void mega(
    const float* __restrict__ edge,
    u32x4* __restrict__ ebf_w, const uint4* __restrict__ ebf_r,
    float* __restrict__ partial,
    const float* __restrict__ nodes0,
    const float* __restrict__ mask,
    const float* __restrict__ w_ih, const float* __restrict__ w_hh,
    const float* __restrict__ b_ih, const float* __restrict__ b_hh,
    int cvt_b,                       // batch to convert (-1: none)
    int gru_b, float* __restrict__ gru_out,   // step-1 GRU batch
    int sb0, const float* __restrict__ sin0, float* __restrict__ sout0,
    int sb1, const float* __restrict__ sin1, float* __restrict__ sout1,
    int sb2, const float* __restrict__ sin2, float* __restrict__ sout2,
    int sb3, const float* __restrict__ sin3, float* __restrict__ sout3)
{
    int blk = blockIdx.x;
    const int tid  = threadIdx.x;
    const int lane = tid & 63;
    const int wv   = tid >> 6;

    // ---------------- cvt: 324 blocks x 4 waves, one (i,j) tile per wave ----
    if (cvt_b >= 0) {
        if (blk < 324) {
            const int tile = blk * 4 + wv;          // 0..1295
            const int i = tile / NN;
            const int j = tile % NN;
            const int b = cvt_b;

            const int p = lane & 7;    // l-block
            const int q = lane >> 3;   // k within octet

            const float* np_ = nodes0 + (b * NN + i) * HH + p * 8;
            const float4 v0 = *(const float4*)(np_);
            const float4 v1 = *(const float4*)(np_ + 4);

            const size_t blkElem = (size_t)((b * NN + i) * NN + j) * (HH * HH);
            const float* __restrict__ Wf = edge + blkElem;
            u32x4* __restrict__ Eb = ebf_w + (blkElem >> 3);

            float acc[8];
            #pragma unroll
            for (int it = 0; it < 8; ++it) acc[it] = 0.f;

            #pragma unroll
            for (int it = 0; it < 8; ++it) {
                const int o = it * 64 + lane;
                const float4 a = *(const float4*)(Wf + (size_t)o * 8);
                const float4 c = *(const float4*)(Wf + (size_t)o * 8 + 4);
                acc[it] = fmaf(a.x, v0.x, acc[it]);
                acc[it] = fmaf(a.y, v0.y, acc[it]);
                acc[it] = fmaf(a.z, v0.z, acc[it]);
                acc[it] = fmaf(a.w, v0.w, acc[it]);
                acc[it] = fmaf(c.x, v1.x, acc[it]);
                acc[it] = fmaf(c.y, v1.y, acc[it]);
                acc[it] = fmaf(c.z, v1.z, acc[it]);
                acc[it] = fmaf(c.w, v1.w, acc[it]);
                u32x4 pk;
                pk.x = pack_bf16_2(a.x, a.y);
                pk.y = pack_bf16_2(a.z, a.w);
                pk.z = pack_bf16_2(c.x, c.y);
                pk.w = pack_bf16_2(c.z, c.w);
                Eb[o] = pk;
            }

            #pragma unroll
            for (int m = 1; m < 8; m <<= 1) {
                #pragma unroll
                for (int it = 0; it < 8; ++it)
                    acc[it] += __shfl_xor(acc[it], m, 64);
            }

            float outv = acc[0];
            #pragma unroll
            for (int t = 1; t < 8; ++t) outv = (p == t) ? acc[t] : outv;

            // partial[b][j][i][k]
            partial[((size_t)(b * NN + j) * NN + i) * HH + (8 * p + q)] = outv;
            return;
        }
        blk -= 324;
    }

    // ---------------- gru1: 9 blocks x 4 nodes ----------------
    if (gru_b >= 0) {
        if (blk < 9) {
            __shared__ float gms[4][HH];
            __shared__ float ghs[4][HH];
            const int node = blk * 4 + wv;          // j within batch
            const int bj = gru_b * NN + node;
            const float* pp = partial + (size_t)bj * NN * HH;
            float m = 0.f;
            #pragma unroll
            for (int i = 0; i < NN; ++i)
                m += pp[i * HH + lane];
            gms[wv][lane] = m * INVN2;
            ghs[wv][lane] = nodes0[bj * HH + lane];
            __syncthreads();
            const float o = gru_lane(gms[wv], ghs[wv], lane, w_ih, w_hh, b_ih, b_hh);
            gru_out[bj * HH + lane] = o * mask[bj];
            return;
        }
        blk -= 9;
    }

    // ---------------- step slots: 36 blocks each ----------------
    int sb = -1; const float* sin = nullptr; float* sout = nullptr;
    if (sb0 >= 0) { if (blk < 36) { sb = sb0; sin = sin0; sout = sout0; } else blk -= 36; }
    if (sb < 0 && sb1 >= 0) { if (blk < 36) { sb = sb1; sin = sin1; sout = sout1; } else blk -= 36; }
    if (sb < 0 && sb2 >= 0) { if (blk < 36) { sb = sb2; sin = sin2; sout = sout2; } else blk -= 36; }
    if (sb < 0 && sb3 >= 0) { if (blk < 36) { sb = sb3; sin = sin3; sout = sout3; } else blk -= 36; }
    if (sb < 0) return;

    {
        const int j  = blk;
        const int b  = sb;
        const int bj = b * NN + j;

        __shared__ float part[4][HH];
        __shared__ float ms[HH];
        __shared__ float hs[HH];

        const int l8 = lane & 7;

        float acc[8];
        #pragma unroll
        for (int it = 0; it < 8; ++it) acc[it] = 0.f;

        for (int ii = 0; ii < 9; ++ii) {
            const int i = wv * 9 + ii;
            const float* np_ = sin + (b * NN + i) * HH + l8 * 8;
            const float4 v0 = *(const float4*)(np_);
            const float4 v1 = *(const float4*)(np_ + 4);
            const size_t blkElem = (size_t)((b * NN + i) * NN + j) * (HH * HH);
            const uint4* __restrict__ Wb = ebf_r + (blkElem >> 3);
            #pragma unroll
            for (int it = 0; it < 8; ++it) {
                const uint4 w = Wb[it * 64 + lane];
                acc[it] = fmaf(__uint_as_float(w.x << 16),          v0.x, acc[it]);
                acc[it] = fmaf(__uint_as_float(w.x & 0xffff0000u),  v0.y, acc[it]);
                acc[it] = fmaf(__uint_as_float(w.y << 16),          v0.z, acc[it]);
                acc[it] = fmaf(__uint_as_float(w.y & 0xffff0000u),  v0.w, acc[it]);
                acc[it] = fmaf(__uint_as_float(w.z << 16),          v1.x, acc[it]);
                acc[it] = fmaf(__uint_as_float(w.z & 0xffff0000u),  v1.y, acc[it]);
                acc[it] = fmaf(__uint_as_float(w.w << 16),          v1.z, acc[it]);
                acc[it] = fmaf(__uint_as_float(w.w & 0xffff0000u),  v1.w, acc[it]);
            }
        }

        #pragma unroll
        for (int m = 1; m < 8; m <<= 1) {
            #pragma unroll
            for (int it = 0; it < 8; ++it)
                acc[it] += __shfl_xor(acc[it], m, 64);
        }

        const int p  = lane & 7;
        const int gq = lane >> 3;
        float outv = acc[0];
        #pragma unroll
        for (int tt = 1; tt < 8; ++tt) outv = (p == tt) ? acc[tt] : outv;
        part[wv][8 * p + gq] = outv;

        __syncthreads();

        if (tid < HH) {
            const float m = part[0][tid] + part[1][tid] + part[2][tid] + part[3][tid];
            ms[tid] = m * INVN2;
            hs[tid] = sin[bj * HH + tid];
        }
        __syncthreads();

        if (tid < HH) {
            const float o = gru_lane(ms, hs, tid, w_ih, w_hh, b_ih, b_hh);
            sout[bj * HH + tid] = o * mask[bj];
        }
    }
}

extern "C" void kernel_launch(void* const* d_in, const int* in_sizes, int n_in,
                              void* d_out, int out_size, void* d_ws, size_t ws_size,
                              hipStream_t stream) {
    const float* edge   = (const float*)d_in[0];
    const float* nodes0 = (const float*)d_in[1];
    const float* mask   = (const float*)d_in[2];
    const float* w_ih   = (const float*)d_in[3];
    const float* w_hh   = (const float*)d_in[4];
    const float* b_ih   = (const float*)d_in[5];
    const float* b_hh   = (const float*)d_in[6];
    float* out = (float*)d_out;

    float* ws = (float*)d_ws;
    const int nodes_elems   = NBJ * HH;                 // 18432
    const size_t partial_elems = (size_t)NBJ * NN * HH; // 663552
    float* partial = ws;
    float* n1 = ws + partial_elems;
    float* n2 = n1 + nodes_elems;
    float* n3 = n2 + nodes_elems;
    float* n4 = n3 + nodes_elems;
    float* ebf_f = n4 + nodes_elems;                    // bf16 copy ~85 MB
    u32x4* ebf_w = (u32x4*)ebf_f;
    const uint4* ebf_r = (const uint4*)ebf_f;

    float* nin[6];  // nodes_{s-1} for step s: s=2 -> n1, ..., s=5 -> n4
    nin[2] = n1; nin[3] = n2; nin[4] = n3; nin[5] = n4;
    float* nout[6]; // nodes_s: s=2 -> n2, ..., s=5 -> out
    nout[2] = n2; nout[3] = n3; nout[4] = n4; nout[5] = out;

    for (int t = 0; t < 13; ++t) {
        const int cvt_b = (t < BB) ? t : -1;
        const int gru_b = (t - 1 >= 0 && t - 1 < BB) ? (t - 1) : -1;
        int sb[4] = {-1, -1, -1, -1};
        const float* sin[4] = {nullptr, nullptr, nullptr, nullptr};
        float* sout[4] = {nullptr, nullptr, nullptr, nullptr};
        int nblk = 0;
        if (cvt_b >= 0) nblk += 324;
        if (gru_b >= 0) nblk += 9;
        for (int s = 2; s <= 5; ++s) {
            const int b = t - s;
            const int slot = s - 2;
            if (b >= 0 && b < BB) {
                sb[slot] = b;
                sin[slot] = nin[s];
                sout[slot] = nout[s];
                nblk += 36;
            }
        }
        if (nblk == 0) continue;
        mega<<<nblk, 256, 0, stream>>>(
            edge, ebf_w, ebf_r, partial, nodes0, mask,
            w_ih, w_hh, b_ih, b_hh,
            cvt_b, gru_b, n1,
            sb[0], sin[0], sout[0],
            sb[1], sin[1], sout[1],
            sb[2], sin[2], sout[2],
            sb[3], sin[3], sout[3]);
    }
}

// Round 19
// 139.527 us; speedup vs baseline: 1.5277x; 1.5277x over previous
//
#include <hip/hip_runtime.h>
#include <hip/hip_bf16.h>

// MPNN: B=8, N=36, H=64, STEPS=5
// messages[b,j,k] = (1/N^2) * sum_{i,l} edge[b,i,j,k,l] * nodes[b,i,l]
// nodes = GRUCell(messages, nodes) * mask, repeated STEPS times.
//
// Structure (6 launches) — best-known (R11) + 8-deep load ILP in K1:
//  K1: einsum_f32_cvt, 3456x64: per (b,i,j) 64x64 block, ALL 16 loads (8
//      octets x 32B) issued before any compute/store -> max loads in flight,
//      store backlog never blocks a load wait. Emits bf16 copy + partials.
//  K2: gru_step, 288x64: reduce 12 partials + GRU -> nodes1.
//  K3..K6: step_bf16 fused einsum+GRU on the cache-resident bf16 copy
//      (~9 us each, measured R8).

#define BB 8
#define NN 36
#define HH 64
#define GG 12            // i-groups per (b,j) for K1
#define IPG (NN / GG)    // 3
#define WAVES 4          // waves/block in fused steps
#define IPW (NN / WAVES) // 9
#define NBJ (BB * NN)    // 288
#define INVN2 (1.0f / (float)(NN * NN))

typedef unsigned u32x4 __attribute__((ext_vector_type(4)));

__device__ __forceinline__ unsigned pack_bf16_2(float lo, float hi) {
    // __float2bfloat16 is RNE; compiler fuses pairs into v_cvt_pk_bf16_f32
    __hip_bfloat16 a = __float2bfloat16(lo);
    __hip_bfloat16 b = __float2bfloat16(hi);
    unsigned ua = *reinterpret_cast<unsigned short*>(&a);
    unsigned ub = *reinterpret_cast<unsigned short*>(&b);
    return ua | (ub << 16);
}

// GRU cell for one node; lane t computes output dim t from LDS-staged
// message (ms) and hidden (hs) vectors. Rows t, t+64, t+128 of w_ih/w_hh.
__device__ __forceinline__ float gru_lane(
    const float* __restrict__ ms, const float* __restrict__ hs, int t,
    const float* __restrict__ w_ih, const float* __restrict__ w_hh,
    const float* __restrict__ b_ih, const float* __restrict__ b_hh)
{
    float gi0 = b_ih[t], gi1 = b_ih[HH + t], gi2 = b_ih[2 * HH + t];
    float gh0 = b_hh[t], gh1 = b_hh[HH + t], gh2 = b_hh[2 * HH + t];

    const float4* __restrict__ wi0 = (const float4*)(w_ih + (0 * HH + t) * HH);
    const float4* __restrict__ wi1 = (const float4*)(w_ih + (1 * HH + t) * HH);
    const float4* __restrict__ wi2 = (const float4*)(w_ih + (2 * HH + t) * HH);
    const float4* __restrict__ wh0 = (const float4*)(w_hh + (0 * HH + t) * HH);
    const float4* __restrict__ wh1 = (const float4*)(w_hh + (1 * HH + t) * HH);
    const float4* __restrict__ wh2 = (const float4*)(w_hh + (2 * HH + t) * HH);

    #pragma unroll
    for (int k4 = 0; k4 < HH / 4; ++k4) {
        const float4 mv = *(const float4*)&ms[k4 * 4];
        const float4 hv = *(const float4*)&hs[k4 * 4];
        float4 a;
        a = wi0[k4]; gi0 += a.x * mv.x + a.y * mv.y + a.z * mv.z + a.w * mv.w;
        a = wi1[k4]; gi1 += a.x * mv.x + a.y * mv.y + a.z * mv.z + a.w * mv.w;
        a = wi2[k4]; gi2 += a.x * mv.x + a.y * mv.y + a.z * mv.z + a.w * mv.w;
        a = wh0[k4]; gh0 += a.x * hv.x + a.y * hv.y + a.z * hv.z + a.w * hv.w;
        a = wh1[k4]; gh1 += a.x * hv.x + a.y * hv.y + a.z * hv.z + a.w * hv.w;
        a = wh2[k4]; gh2 += a.x * hv.x + a.y * hv.y + a.z * hv.z + a.w * hv.w;
    }
    const float r = 1.f / (1.f + expf(-(gi0 + gh0)));
    const float z = 1.f / (1.f + expf(-(gi1 + gh1)));
    const float n = tanhf(gi2 + r * gh2);
    return (1.f - z) * n + z * hs[t];
}

// ---------------------------------------------------------------------------
// K1: einsum on f32 edge + emit bf16 copy, 8-deep batched loads.
// grid = 3456 x 64. bid = (b*NN+j)*GG + g. Per (b,i,j) 64x64 f32 block:
// lane handles octet o = it*64+lane (it=0..7): k = 8*it+(lane>>3),
// l = 8*(lane&7)+m. Phase 1: issue ALL 16 16B loads. Phase 2: 64 FMA +
// 24 cvt_pk + 8 16B stores. Butterfly over low 3 lane bits sums l-blocks;
// lane (q=lane>>3,p=lane&7) writes k = 8p+q from acc[p].
// ---------------------------------------------------------------------------
__global__ __launch_bounds__(64) void einsum_f32_cvt(
    const float* __restrict__ edge,
    const float* __restrict__ nodes,
    float* __restrict__ partial,
    u32x4* __restrict__ ebf)
{
    const int lane = threadIdx.x;
    const int bid  = blockIdx.x;
    const int g = bid % GG;
    const int j = (bid / GG) % NN;
    const int b = bid / (GG * NN);

    const int p = lane & 7;    // l-block
    const int q = lane >> 3;   // k within octet

    float acc[8];
    #pragma unroll
    for (int it = 0; it < 8; ++it) acc[it] = 0.f;

    #pragma unroll
    for (int ii = 0; ii < IPG; ++ii) {
        const int i = g * IPG + ii;
        const float* np_ = nodes + (b * NN + i) * HH + p * 8;
        const float4 v0 = *(const float4*)(np_);
        const float4 v1 = *(const float4*)(np_ + 4);
        const size_t blkElem = (size_t)((b * NN + i) * NN + j) * (HH * HH);
        const float* __restrict__ Wf = edge + blkElem;
        u32x4* __restrict__ Eb = ebf + (blkElem >> 3);

        // phase 1: issue all 16 loads (8 octets x 2 float4)
        float4 A[8], C[8];
        #pragma unroll
        for (int it = 0; it < 8; ++it) {
            const int o = it * 64 + lane;
            A[it] = *(const float4*)(Wf + (size_t)o * 8);
            C[it] = *(const float4*)(Wf + (size_t)o * 8 + 4);
        }

        // phase 2: compute + store
        #pragma unroll
        for (int it = 0; it < 8; ++it) {
            acc[it] = fmaf(A[it].x, v0.x, acc[it]);
            acc[it] = fmaf(A[it].y, v0.y, acc[it]);
            acc[it] = fmaf(A[it].z, v0.z, acc[it]);
            acc[it] = fmaf(A[it].w, v0.w, acc[it]);
            acc[it] = fmaf(C[it].x, v1.x, acc[it]);
            acc[it] = fmaf(C[it].y, v1.y, acc[it]);
            acc[it] = fmaf(C[it].z, v1.z, acc[it]);
            acc[it] = fmaf(C[it].w, v1.w, acc[it]);
            u32x4 pk;
            pk.x = pack_bf16_2(A[it].x, A[it].y);
            pk.y = pack_bf16_2(A[it].z, A[it].w);
            pk.z = pack_bf16_2(C[it].x, C[it].y);
            pk.w = pack_bf16_2(C[it].z, C[it].w);
            Eb[it * 64 + lane] = pk;
        }
    }

    // sum across the 8 l-blocks (low 3 lane bits)
    #pragma unroll
    for (int m = 1; m < 8; m <<= 1) {
        #pragma unroll
        for (int it = 0; it < 8; ++it)
            acc[it] += __shfl_xor(acc[it], m, 64);
    }

    // lane (q,p) takes acc[p] -> k = 8*p + q
    float outv = acc[0];
    #pragma unroll
    for (int t = 1; t < 8; ++t) outv = (p == t) ? acc[t] : outv;

    partial[(size_t)bid * HH + (8 * p + q)] = outv;
}

// ---------------------------------------------------------------------------
// K2: reduce 12 partials + GRU -> nodes1. grid = 288 x 64.
// ---------------------------------------------------------------------------
__global__ __launch_bounds__(64) void gru_step(
    const float* __restrict__ partial,
    const float* __restrict__ nodes_in,
    const float* __restrict__ mask,
    const float* __restrict__ w_ih, const float* __restrict__ w_hh,
    const float* __restrict__ b_ih, const float* __restrict__ b_hh,
    float* __restrict__ nodes_out)
{
    const int t  = threadIdx.x;
    const int bj = blockIdx.x;

    float m = 0.f;
    #pragma unroll
    for (int g = 0; g < GG; ++g)
        m += partial[((size_t)bj * GG + g) * HH + t];

    __shared__ float ms[HH];
    __shared__ float hs[HH];
    ms[t] = m * INVN2;
    hs[t] = nodes_in[bj * HH + t];
    __syncthreads();

    const float o = gru_lane(ms, hs, t, w_ih, w_hh, b_ih, b_hh);
    nodes_out[bj * HH + t] = o * mask[bj];
}

// ---------------------------------------------------------------------------
// K3..K6: einsum on bf16 edge copy + in-block GRU.
// grid = 288 x 256 (4 waves); wave w streams i = 9w..9w+8. (~9 us each, R8)
// ---------------------------------------------------------------------------
__global__ __launch_bounds__(256, 2) void step_bf16(
    const uint4* __restrict__ ebf,
    const float* __restrict__ nodes_in,
    const float* __restrict__ mask,
    const float* __restrict__ w_ih, const float* __restrict__ w_hh,
    const float* __restrict__ b_ih, const float* __restrict__ b_hh,
    float* __restrict__ nodes_out)
{
    const int tid  = threadIdx.x;
    const int lane = tid & 63;
    const int wv   = tid >> 6;
    const int bj = blockIdx.x;
    const int j  = bj % NN;
    const int b  = bj / NN;

    __shared__ float part[WAVES][HH];
    __shared__ float ms[HH];
    __shared__ float hs[HH];

    const int l8 = lane & 7;

    float acc[8];
    #pragma unroll
    for (int it = 0; it < 8; ++it) acc[it] = 0.f;

    for (int ii = 0; ii < IPW; ++ii) {
        const int i = wv * IPW + ii;
        const float* np_ = nodes_in + (b * NN + i) * HH + l8 * 8;
        const float4 v0 = *(const float4*)(np_);
        const float4 v1 = *(const float4*)(np_ + 4);
        const size_t blkElem = (size_t)((b * NN + i) * NN + j) * (HH * HH);
        const uint4* __restrict__ Wb = ebf + (blkElem >> 3);
        #pragma unroll
        for (int it = 0; it < 8; ++it) {
            const uint4 w = Wb[it * 64 + lane];
            acc[it] = fmaf(__uint_as_float(w.x << 16),          v0.x, acc[it]);
            acc[it] = fmaf(__uint_as_float(w.x & 0xffff0000u),  v0.y, acc[it]);
            acc[it] = fmaf(__uint_as_float(w.y << 16),          v0.z, acc[it]);
            acc[it] = fmaf(__uint_as_float(w.y & 0xffff0000u),  v0.w, acc[it]);
            acc[it] = fmaf(__uint_as_float(w.z << 16),          v1.x, acc[it]);
            acc[it] = fmaf(__uint_as_float(w.z & 0xffff0000u),  v1.y, acc[it]);
            acc[it] = fmaf(__uint_as_float(w.w << 16),          v1.z, acc[it]);
            acc[it] = fmaf(__uint_as_float(w.w & 0xffff0000u),  v1.w, acc[it]);
        }
    }

    #pragma unroll
    for (int m = 1; m < 8; m <<= 1) {
        #pragma unroll
        for (int it = 0; it < 8; ++it)
            acc[it] += __shfl_xor(acc[it], m, 64);
    }

    const int p  = lane & 7;
    const int gq = lane >> 3;
    float outv = acc[0];
    #pragma unroll
    for (int tt = 1; tt < 8; ++tt) outv = (p == tt) ? acc[tt] : outv;
    part[wv][8 * p + gq] = outv;

    __syncthreads();

    if (tid < HH) {
        const float m = part[0][tid] + part[1][tid] + part[2][tid] + part[3][tid];
        ms[tid] = m * INVN2;
        hs[tid] = nodes_in[bj * HH + tid];
    }
    __syncthreads();

    if (tid < HH) {
        const float o = gru_lane(ms, hs, tid, w_ih, w_hh, b_ih, b_hh);
        nodes_out[bj * HH + tid] = o * mask[bj];
    }
}

extern "C" void kernel_launch(void* const* d_in, const int* in_sizes, int n_in,
                              void* d_out, int out_size, void* d_ws, size_t ws_size,
                              hipStream_t stream) {
    const float* edge   = (const float*)d_in[0];
    const float* nodes0 = (const float*)d_in[1];
    const float* mask   = (const float*)d_in[2];
    const float* w_ih   = (const float*)d_in[3];
    const float* w_hh   = (const float*)d_in[4];
    const float* b_ih   = (const float*)d_in[5];
    const float* b_hh   = (const float*)d_in[6];
    float* out = (float*)d_out;

    float* ws = (float*)d_ws;
    const int nodes_elems   = BB * NN * HH;            // 18432
    const int partial_elems = NBJ * GG * HH;           // 221184
    float* nodesA  = ws;
    float* nodesB  = ws + nodes_elems;
    float* partial = ws + 2 * nodes_elems;
    float* ebf_f   = partial + partial_elems;          // bf16 edge copy ~85 MB
    u32x4* ebf4w = (u32x4*)ebf_f;
    const uint4* ebf4 = (const uint4*)ebf_f;

    // K1: messages1 -> partial (+ bf16 edge copy), batched-load ILP
    einsum_f32_cvt<<<NBJ * GG, 64, 0, stream>>>(edge, nodes0, partial, ebf4w);
    // K2: nodes1 = GRU(partial, nodes0)
    gru_step<<<NBJ, 64, 0, stream>>>(partial, nodes0, mask,
                                     w_ih, w_hh, b_ih, b_hh, nodesA);
    // K3..K6: fused bf16 steps
    step_bf16<<<NBJ, 256, 0, stream>>>(ebf4, nodesA, mask,
                                       w_ih, w_hh, b_ih, b_hh, nodesB);
    step_bf16<<<NBJ, 256, 0, stream>>>(ebf4, nodesB, mask,
                                       w_ih, w_hh, b_ih, b_hh, nodesA);
    step_bf16<<<NBJ, 256, 0, stream>>>(ebf4, nodesA, mask,
                                       w_ih, w_hh, b_ih, b_hh, nodesB);
    step_bf16<<<NBJ, 256, 0, stream>>>(ebf4, nodesB, mask,
                                       w_ih, w_hh, b_ih, b_hh, out);
}